// Round 5
// baseline (10474.665 us; speedup 1.0000x reference)
//
#include <hip/hip_runtime.h>

#define B_  64
#define S_  256
#define H_  768
#define H4_ 3072
#define D2_ 1536
#define SEG 64
#define USZ (64*2304)

using u16 = unsigned short;
using u32 = unsigned int;
using u64 = unsigned long long;
typedef __attribute__((ext_vector_type(8))) short bf16x8;
typedef __attribute__((ext_vector_type(4))) float f32x4;
typedef __attribute__((ext_vector_type(4))) unsigned int u32x4;

#define DEV __device__ __forceinline__

DEV float bf2f(u16 u){ union{u32 i; float f;} c; c.i = ((u32)u)<<16; return c.f; }
DEV u16 f2bf(float f){ union{float f; u32 i;} c; c.f = f; return (u16)((c.i + 0x7FFFu + ((c.i>>16)&1u)) >> 16); }
DEV float sigm(float x){ return 1.f/(1.f + __expf(-x)); }
DEV float tanh_(float x){ return 2.f/(1.f + __expf(-2.f*x)) - 1.f; }

// agent-scope stores for cross-XCD data publication (write-through to LLC)
DEV void astore32(u16* p, u32 v){ __hip_atomic_store((u32*)p, v, __ATOMIC_RELAXED, __HIP_MEMORY_SCOPE_AGENT); }
DEV int afload(const int* p){ return __hip_atomic_load(p, __ATOMIC_RELAXED, __HIP_MEMORY_SCOPE_AGENT); }

DEV f32x4 mfma16(bf16x8 a, bf16x8 b, f32x4 c){
  return __builtin_amdgcn_mfma_f32_16x16x32_bf16(a, b, c, 0, 0, 0);
}

// stage 48 contiguous u16 (96 B) global->LDS as 6 x 16B vectors.
// NOTE: offsets are u16 ELEMENTS (8 per u32x4) — round-4 bug was +16/+32 gaps.
DEV void stage48(u16* dst, const u16* src){
  u32x4 v0 = *(const u32x4*)(src);
  u32x4 v1 = *(const u32x4*)(src+8);
  u32x4 v2 = *(const u32x4*)(src+16);
  u32x4 v3 = *(const u32x4*)(src+24);
  u32x4 v4 = *(const u32x4*)(src+32);
  u32x4 v5 = *(const u32x4*)(src+40);
  *(u32x4*)(dst)    = v0; *(u32x4*)(dst+8)  = v1;
  *(u32x4*)(dst+16) = v2; *(u32x4*)(dst+24) = v3;
  *(u32x4*)(dst+32) = v4; *(u32x4*)(dst+40) = v5;
}
DEV void stage48z(u16* dst, const u16* src, bool keep){
  const u32x4 z = {0u,0u,0u,0u};
  u32x4 v0 = *(const u32x4*)(src);
  u32x4 v1 = *(const u32x4*)(src+8);
  u32x4 v2 = *(const u32x4*)(src+16);
  u32x4 v3 = *(const u32x4*)(src+24);
  u32x4 v4 = *(const u32x4*)(src+32);
  u32x4 v5 = *(const u32x4*)(src+40);
  if (!keep){ v0=z; v1=z; v2=z; v3=z; v4=z; v5=z; }
  *(u32x4*)(dst)    = v0; *(u32x4*)(dst+8)  = v1;
  *(u32x4*)(dst+16) = v2; *(u32x4*)(dst+24) = v3;
  *(u32x4*)(dst+32) = v4; *(u32x4*)(dst+40) = v5;
}

// group barrier: release own flag, poll group's flags, then agent-acquire fence
// (buffer_inv) so subsequent PLAIN loads see remote sc-stores from this round.
DEV void gbar(int* flags, int slot_me, int slot_base, int n, int ep){
  __threadfence_block();
  __syncthreads();
  if (threadIdx.x == 0)
    __hip_atomic_store(&flags[slot_me*32], ep, __ATOMIC_RELEASE, __HIP_MEMORY_SCOPE_AGENT);
  if ((int)threadIdx.x < n) {
    while (afload(&flags[(slot_base + (int)threadIdx.x)*32]) < ep) {}
  }
  __syncthreads();
  __builtin_amdgcn_fence(__ATOMIC_ACQUIRE, "agent");
}

// ---------------- fp32 -> bf16 convert (strided dst for packing) ---------------
__global__ void k_conv(const float* __restrict__ src, u16* __restrict__ dst,
                       int cols, int sld, int dld){
  const long r = blockIdx.x;
  for (int c = threadIdx.x*4; c < cols; c += 1024) {
    const float* sp = src + r*sld + c;
    float a = sp[0], b = sp[1], cc = sp[2], d = sp[3];
    u64 pack = (u64)f2bf(a) | ((u64)f2bf(b)<<16) | ((u64)f2bf(cc)<<32) | ((u64)f2bf(d)<<48);
    *(u64*)(dst + r*dld + c) = pack;
  }
}

// ---- C(bf16, 4096x3072) = A[b,t0+tt](bf16) @ W(bf16)^T + bias, 128x128 tile ---
__global__ __launch_bounds__(256) void k_gemm(
    const u16* __restrict__ A, const u16* __restrict__ W,
    const float* __restrict__ bias, u16* __restrict__ C, int K, int t0)
{
  __shared__ u16 at[128*40];
  __shared__ u16 bt[128*40];
  const int tid = threadIdx.x;
  const int L = tid & 63, wv = tid >> 6;
  const int mq = wv >> 1, nq = wv & 1;
  const int l16 = L & 15, quad = L >> 4;
  const long mb = blockIdx.y, nb = blockIdx.x;

  f32x4 acc[4][4];
  #pragma unroll
  for (int m=0;m<4;++m)
    #pragma unroll
    for (int n=0;n<4;++n)
      acc[m][n] = (f32x4){0.f,0.f,0.f,0.f};

  const int r = tid >> 1, c0 = (tid & 1) * 16;
  const int fr = (int)mb*128 + r;
  const long arow = ((long)(fr >> 6))*S_ + t0 + (fr & 63);
  const u16* Arow = A + arow*(long)K + c0;
  const u16* Wrow = W + (nb*128 + r)*(long)K + c0;

  for (int kb = 0; kb < K; kb += 32) {
    *(u32x4*)&at[r*40 + c0]     = *(const u32x4*)(Arow + kb);
    *(u32x4*)&at[r*40 + c0 + 8] = *(const u32x4*)(Arow + kb + 8);
    *(u32x4*)&bt[r*40 + c0]     = *(const u32x4*)(Wrow + kb);
    *(u32x4*)&bt[r*40 + c0 + 8] = *(const u32x4*)(Wrow + kb + 8);
    __syncthreads();
    bf16x8 af[4], bfr[4];
    #pragma unroll
    for (int m=0;m<4;++m) af[m]  = *(const bf16x8*)&at[(mq*64 + m*16 + l16)*40 + quad*8];
    #pragma unroll
    for (int n=0;n<4;++n) bfr[n] = *(const bf16x8*)&bt[(nq*64 + n*16 + l16)*40 + quad*8];
    #pragma unroll
    for (int m=0;m<4;++m)
      #pragma unroll
      for (int n=0;n<4;++n)
        acc[m][n] = mfma16(af[m], bfr[n], acc[m][n]);
    __syncthreads();
  }
  #pragma unroll
  for (int n=0;n<4;++n) {
    const long col = nb*128 + nq*64 + n*16 + l16;
    const float bv = bias[col];
    #pragma unroll
    for (int m=0;m<4;++m) {
      const long row0 = mb*128 + mq*64 + m*16 + quad*4;
      #pragma unroll
      for (int rr=0;rr<4;++rr)
        C[(row0+rr)*3072 + col] = f2bf(acc[m][n][rr] + bv);
    }
  }
}

// ------- persistent bilstm segment: 192 wgs = 2 dirs x 2 bhalf x 48 slices -----
// 512 thr = 8 waves = gate q(4) x k-half kh(2). Plain vectorized staging; the
// gbar's acquire fence makes each round's remote sc-stores visible.
__global__ __launch_bounds__(512,2) void k_bilstm(
    const u16* __restrict__ Gf, const u16* __restrict__ Gb,
    const u16* __restrict__ Whhf, const u16* __restrict__ Whhb,
    const u16* __restrict__ h0, u16* __restrict__ lstm,
    float* __restrict__ cstf, float* __restrict__ cstb,
    int* __restrict__ flags, int t0f, int tb0, int ep0)
{
  __shared__ __align__(16) u16 ab[2][32*392];   // 2 staging bufs (32 x 384 +pad)
  float* gbuf = (float*)ab;                     // 16KB alias on ab[0]
  const int wg = blockIdx.x;
  const int dir = wg / 96, rem = wg % 96, mh = rem / 48, s = rem % 48;
  const int tid = threadIdx.x;
  const int wave = tid >> 6, q = wave & 3, kh = wave >> 2;
  const int L = tid & 63, l16 = L & 15, quad = L >> 4;
  const int su = tid & 255, srw = su >> 3, scl = (su & 7) * 48;

  const u16* Gsrc = dir ? Gb : Gf;
  const u16* W    = dir ? Whhb : Whhf;
  float* cst      = dir ? cstb : cstf;

  bf16x8 bfr[12];
  {
    const u16* wr = W + (long)(q*H_ + s*16 + l16)*H_ + kh*384 + quad*8;
    #pragma unroll
    for (int kk=0;kk<12;++kk) bfr[kk] = *(const bf16x8*)(wr + kk*32);
  }

  const int lb = tid >> 3, cdl = (tid & 7) * 2;
  const int eb = mh*32 + lb, col = s*16 + cdl;
  const bool ew = (tid < 256);
  float creg[2] = {0.f, 0.f};
  if (ew){ creg[0] = cst[eb*H_ + col]; creg[1] = cst[eb*H_ + col + 1]; }

  u32 g0=0,g1=0,g2=0,g3=0;
  if (ew){
    const int tp0 = dir ? (tb0 + SEG-1) : t0f;
    const int gidx = eb*SEG + (dir ? (tp0 - tb0) : (tp0 - t0f));
    const u16* grow = Gsrc + (long)gidx*H4_ + col;
    g0 = *(const u32*)(grow);      g1 = *(const u32*)(grow + H_);
    g2 = *(const u32*)(grow+2*H_); g3 = *(const u32*)(grow+3*H_);
  }

  for (int t=0; t<SEG; ++t) {
    const int tp = dir ? (tb0 + SEG-1 - t) : (t0f + t);
    const bool first = dir ? (tp == S_-1) : (tp == 0);
    const u16* hbase; long ldh;
    if (first){ hbase = h0 + dir*H_; ldh = D2_; }
    else {
      const int tprev = dir ? (tp+1) : (tp-1);
      hbase = lstm + (long)tprev*D2_ + dir*H_;
      ldh = (long)S_*D2_;
    }
    const u16* hrow = hbase + (long)(mh*32 + srw)*ldh + scl;

    if (kh == 0){                           // stage chunk0 (cols 0..384)
      stage48(&ab[0][srw*392 + scl], hrow);
    }
    __syncthreads();
    f32x4 acc[2];
    acc[0] = (f32x4){0.f,0.f,0.f,0.f}; acc[1] = acc[0];
    if (kh == 0){                           // mfma chunk0 || stage chunk1
      #pragma unroll
      for (int kk=0;kk<12;++kk)
        #pragma unroll
        for (int m=0;m<2;++m){
          bf16x8 a = *(const bf16x8*)&ab[0][(m*16+l16)*392 + kk*32 + quad*8];
          acc[m] = mfma16(a, bfr[kk], acc[m]);
        }
    } else {
      stage48(&ab[1][srw*392 + scl], hrow + 384);
    }
    __syncthreads();
    if (kh == 1){
      #pragma unroll
      for (int kk=0;kk<12;++kk)
        #pragma unroll
        for (int m=0;m<2;++m){
          bf16x8 a = *(const bf16x8*)&ab[1][(m*16+l16)*392 + kk*32 + quad*8];
          acc[m] = mfma16(a, bfr[kk], acc[m]);
        }
    }
    __syncthreads();
    #pragma unroll
    for (int m=0;m<2;++m)
      #pragma unroll
      for (int rr=0;rr<4;++rr)
        gbuf[(q*2+kh)*512 + (m*16+quad*4+rr)*16 + l16] = acc[m][rr];
    __syncthreads();
    if (ew){
      u32 gr[4] = {g0,g1,g2,g3};
      u32 hp = 0;
      #pragma unroll
      for (int i=0;i<2;++i){
        float gv[4];
        #pragma unroll
        for (int qq=0;qq<4;++qq)
          gv[qq] = gbuf[(qq*2+0)*512 + lb*16 + cdl+i]
                 + gbuf[(qq*2+1)*512 + lb*16 + cdl+i]
                 + bf2f((u16)(gr[qq] >> (16*i)));
        const float c = sigm(gv[1])*creg[i] + sigm(gv[0])*tanh_(gv[2]);
        creg[i] = c;
        const float h = sigm(gv[3])*tanh_(c);
        hp |= ((u32)f2bf(h)) << (16*i);
      }
      astore32(lstm + ((long)eb*S_ + tp)*D2_ + dir*H_ + col, hp);
      // carry next round's G prefetch (overlaps the barrier); last-t value unused
      const int t2 = t + 1;
      const int tp2 = dir ? (tb0 + SEG-1 - t2) : (t0f + t2);
      const long gidx2 = (long)eb*SEG + (dir ? (tp2 - tb0) : (tp2 - t0f));
      const u16* grow2 = Gsrc + gidx2*H4_ + col;
      g0 = *(const u32*)(grow2);      g1 = *(const u32*)(grow2 + H_);
      g2 = *(const u32*)(grow2+2*H_); g3 = *(const u32*)(grow2+3*H_);
    }
    gbar(flags, wg, dir*96, 96, ep0 + t + 1);
  }
  if (ew){ cst[eb*H_ + col] = creg[0]; cst[eb*H_ + col + 1] = creg[1]; }
}

// -------- persistent decode: 192 wgs = role(sub/word) x 2 bhalf x 48 slices ----
// role0 computes subword(t=r); role1 computes word(t=r-1). Decoupled barriers:
// role0 waits {role0 >= r, role1(half) >= r-1 (triple-buffer clobber guard)};
// role1 waits {role0 >= r, role1(half) >= r}. U is triple-buffered (64x2304:
// [h1|c1|Wh]); Sh eliminated (role0 masks h1 rows by golds during staging).
__global__ __launch_bounds__(512,2) void k_decode(
    const u16* __restrict__ Gsub, const u16* __restrict__ Wsub,
    const u16* __restrict__ Wwrd, const float* __restrict__ wbias,
    const float* __restrict__ clsW, const int* __restrict__ golds,
    u16* __restrict__ U,
    float* __restrict__ scS, float* __restrict__ wcS, float* __restrict__ whS,
    float* __restrict__ partials, int* __restrict__ flags, int r0)
{
  __shared__ __align__(16) u16 ab[2][32*392];
  float* gbuf = (float*)ab;
  const int wg = blockIdx.x;
  const int role = wg / 96, rem = wg % 96, mh = rem / 48, s = rem % 48;
  const int tid = threadIdx.x;
  const int wave = tid >> 6, q = wave & 3, kh = wave >> 2;
  const int L = tid & 63, l16 = L & 15, quad = L >> 4;
  const int su = tid & 255, srw = su >> 3, scl = (su & 7) * 48;
  const int lb = tid >> 3, cdl = (tid & 7)*2;
  const int eb = mh*32 + lb, col = s*16 + cdl;
  const bool ew = (tid < 256);
  const int sb = mh*32 + srw;            // batch of this thread's staged row

  bf16x8 wfr[36];
  float st0[2] = {0.f,0.f}, st1[2] = {0.f,0.f}, st2[2] = {0.f,0.f};
  float wbv[4][2], clv[2][2];
  if (role == 0){
    const u16* wr = Wsub + (long)(q*H_ + s*16 + l16)*H_ + kh*384 + quad*8;
    #pragma unroll
    for (int kk=0;kk<12;++kk) wfr[kk] = *(const bf16x8*)(wr + kk*32);
    if (ew){ st0[0] = scS[eb*H_+col]; st0[1] = scS[eb*H_+col+1]; }
  } else {
    const u16* wr = Wwrd + (long)(q*H_ + s*16 + l16)*2304 + kh*384 + quad*8;
    #pragma unroll
    for (int cc=0;cc<3;++cc)
      #pragma unroll
      for (int kk=0;kk<12;++kk)
        wfr[cc*12+kk] = *(const bf16x8*)(wr + cc*768 + kk*32);
    if (ew){
      st1[0] = wcS[eb*H_+col]; st1[1] = wcS[eb*H_+col+1];
      st2[0] = whS[eb*H_+col]; st2[1] = whS[eb*H_+col+1];
      #pragma unroll
      for (int qq=0;qq<4;++qq){ wbv[qq][0]=wbias[qq*H_+col]; wbv[qq][1]=wbias[qq*H_+col+1]; }
      clv[0][0]=clsW[col]; clv[0][1]=clsW[col+1];
      clv[1][0]=clsW[2304+col]; clv[1][1]=clsW[2304+col+1];
    }
  }

  int stg_g = golds[sb*S_ + ((r0 < 255) ? r0 : 255)];   // staging mask carry (role0)

  for (int rr=0; rr<SEG; ++rr){
    const int r = r0 + rr;
    // ---- decoupled waits ----
    if (tid < 144){
      int idx, tgt;
      if (tid < 96){ idx = tid; tgt = r; }
      else { idx = 96 + mh*48 + (tid - 96); tgt = (role==0) ? (r-1) : r; }
      while (afload(&flags[idx*32]) < tgt) {}
    }
    __syncthreads();
    __builtin_amdgcn_fence(__ATOMIC_ACQUIRE, "agent");

    const u16* Uprev = U + ((r+2)%3)*USZ;
    u16*       Ucur  = U + (r%3)*USZ;

    if (role == 0){
      if (r <= 254){
        // early issue: gate prefetch + epilogue keep
        u32 g0=0,g1=0,g2=0,g3=0; int gld_e = 0;
        if (ew){
          gld_e = golds[eb*S_ + r + 1];
          const u16* grow = Gsub + ((long)eb*SEG + rr)*H4_ + col;
          g0 = *(const u32*)(grow);      g1 = *(const u32*)(grow + H_);
          g2 = *(const u32*)(grow+2*H_); g3 = *(const u32*)(grow+3*H_);
        }
        const bool keep_s = (r > 0) && (stg_g == 0);
        const u16* urow = Uprev + (long)sb*2304 + scl;
        if (kh == 0){                        // stage masked h1 chunk0
          stage48z(&ab[0][srw*392 + scl], urow, keep_s);
        }
        __syncthreads();
        f32x4 acc[2];
        acc[0] = (f32x4){0.f,0.f,0.f,0.f}; acc[1] = acc[0];
        if (kh == 0){
          #pragma unroll
          for (int kk=0;kk<12;++kk)
            #pragma unroll
            for (int m=0;m<2;++m){
              bf16x8 a = *(const bf16x8*)&ab[0][(m*16+l16)*392 + kk*32 + quad*8];
              acc[m] = mfma16(a, wfr[kk], acc[m]);
            }
        } else {                             // stage masked h1 chunk1
          stage48z(&ab[1][srw*392 + scl], urow + 384, keep_s);
        }
        __syncthreads();
        if (kh == 1){
          #pragma unroll
          for (int kk=0;kk<12;++kk)
            #pragma unroll
            for (int m=0;m<2;++m){
              bf16x8 a = *(const bf16x8*)&ab[1][(m*16+l16)*392 + kk*32 + quad*8];
              acc[m] = mfma16(a, wfr[kk], acc[m]);
            }
        }
        __syncthreads();
        stg_g = golds[sb*S_ + ((r+1 < 255) ? r+1 : 255)];  // carry for next round
        #pragma unroll
        for (int m=0;m<2;++m)
          #pragma unroll
          for (int r4=0;r4<4;++r4)
            gbuf[(q*2+kh)*512 + (m*16+quad*4+r4)*16 + l16] = acc[m][r4];
        __syncthreads();
        if (ew){
          const bool keep = (gld_e == 0);
          u32 gr[4] = {g0,g1,g2,g3};
          u32 hp=0, cp=0;
          #pragma unroll
          for (int i=0;i<2;++i){
            float gv[4];
            #pragma unroll
            for (int qq=0;qq<4;++qq)
              gv[qq] = gbuf[(qq*2+0)*512 + lb*16 + cdl+i]
                     + gbuf[(qq*2+1)*512 + lb*16 + cdl+i]
                     + bf2f((u16)(gr[qq] >> (16*i)));
            const float c1 = sigm(gv[1])*st0[i] + sigm(gv[0])*tanh_(gv[2]);
            const float h1 = sigm(gv[3])*tanh_(c1);
            st0[i] = keep ? c1 : 0.f;
            hp |= ((u32)f2bf(h1)) << (16*i);
            cp |= ((u32)f2bf(c1)) << (16*i);
          }
          astore32(Ucur + (long)eb*2304 + col, hp);
          astore32(Ucur + (long)eb*2304 + H_ + col, cp);
        }
      }
    } else {
      if (r >= 1){
        int gld = 0;
        if (ew) gld = golds[eb*S_ + r];
        const u16* urow = Uprev + (long)sb*2304;
        if (kh == 0){                        // pre-stage chunk0
          stage48(&ab[0][srw*392 + scl], urow + scl);
        }
        __syncthreads();
        f32x4 acc[2];
        acc[0] = (f32x4){0.f,0.f,0.f,0.f}; acc[1] = acc[0];
        #pragma unroll
        for (int p=0;p<6;++p){
          if ((p & 1) == kh){                // consume chunk p
            const int cc = p >> 1;
            #pragma unroll
            for (int kk=0;kk<12;++kk)
              #pragma unroll
              for (int m=0;m<2;++m){
                bf16x8 a = *(const bf16x8*)&ab[p&1][(m*16+l16)*392 + kk*32 + quad*8];
                acc[m] = mfma16(a, wfr[cc*12+kk], acc[m]);
              }
          } else if (p < 5){                 // stage chunk p+1
            stage48(&ab[(p+1)&1][srw*392 + scl], urow + (p+1)*384 + scl);
          }
          __syncthreads();
        }
        #pragma unroll
        for (int m=0;m<2;++m)
          #pragma unroll
          for (int r4=0;r4<4;++r4)
            gbuf[(q*2+kh)*512 + (m*16+quad*4+r4)*16 + l16] = acc[m][r4];
        __syncthreads();
        if (ew){
          const bool keep = (gld == 0);
          const int tp = r - 1;
          float p0 = 0.f, p1 = 0.f;
          u32 wp = 0;
          #pragma unroll
          for (int i=0;i<2;++i){
            float gv[4];
            #pragma unroll
            for (int qq=0;qq<4;++qq)
              gv[qq] = gbuf[(qq*2+0)*512 + lb*16 + cdl+i]
                     + gbuf[(qq*2+1)*512 + lb*16 + cdl+i]
                     + wbv[qq][i];
            const float wc1 = sigm(gv[1])*st1[i] + sigm(gv[0])*tanh_(gv[2]);
            const float wh1 = sigm(gv[3])*tanh_(wc1);
            st1[i] = keep ? st1[i] : wc1;
            st2[i] = keep ? st2[i] : wh1;
            p0 += wh1 * clv[0][i];
            p1 += wh1 * clv[1][i];
            wp |= ((u32)f2bf(st2[i])) << (16*i);
          }
          astore32(Ucur + (long)eb*2304 + D2_ + col, wp);
          p0 += __shfl_xor(p0, 1); p0 += __shfl_xor(p0, 2); p0 += __shfl_xor(p0, 4);
          p1 += __shfl_xor(p1, 1); p1 += __shfl_xor(p1, 2); p1 += __shfl_xor(p1, 4);
          if ((tid & 7) == 0){
            float* pp = partials + ((long)(tp*48 + s)*64 + eb)*2;
            pp[0] = p0; pp[1] = p1;
          }
        }
      }
    }
    // ---- release own flag ----
    __threadfence_block();
    __syncthreads();
    if (tid == 0)
      __hip_atomic_store(&flags[wg*32], r+1, __ATOMIC_RELEASE, __HIP_MEMORY_SCOPE_AGENT);
  }
  if (ew){
    if (role == 0){
      scS[eb*H_+col] = st0[0]; scS[eb*H_+col+1] = st0[1];
    } else {
      wcS[eb*H_+col] = st1[0]; wcS[eb*H_+col+1] = st1[1];
      whS[eb*H_+col] = st2[0]; whS[eb*H_+col+1] = st2[1];
    }
  }
}

// ---------------- classifier epilogue: out = first | cls_b + wh-part + x-part --
__global__ __launch_bounds__(256) void k_cls(
    const u16* __restrict__ lstm, const float* __restrict__ partials,
    const float* __restrict__ clsW, const float* __restrict__ clsb,
    float* __restrict__ out)
{
  const int ts = blockIdx.x;
  const int b  = blockIdx.y;
  const int tid = threadIdx.x;
  if (ts == 0) {
    if (tid == 0) { out[(long)b*S_*2 + 0] = -1.f; out[(long)b*S_*2 + 1] = 1.f; }
    return;
  }
  const int t = ts - 1;
  float s0 = 0.f, s1 = 0.f;
  const u16* xr = lstm + ((long)b*S_ + ts)*D2_;
  for (int k = tid; k < D2_; k += 256) {
    const float xv = bf2f(xr[k]);
    s0 += xv * clsW[768 + k];
    s1 += xv * clsW[2304 + 768 + k];
  }
  if (tid < 48) {
    const float* pr = partials + ((long)(t*48 + tid)*64 + b)*2;
    s0 += pr[0]; s1 += pr[1];
  }
  __shared__ float r0[256], r1[256];
  r0[tid] = s0; r1[tid] = s1; __syncthreads();
  for (int off = 128; off > 0; off >>= 1) {
    if (tid < off) { r0[tid] += r0[tid+off]; r1[tid] += r1[tid+off]; }
    __syncthreads();
  }
  if (tid == 0) {
    out[((long)b*S_ + ts)*2 + 0] = r0[0] + clsb[0];
    out[((long)b*S_ + ts)*2 + 1] = r1[0] + clsb[1];
  }
}

extern "C" void kernel_launch(void* const* d_in, const int* in_sizes, int n_in,
                              void* d_out, int out_size, void* d_ws, size_t ws_size,
                              hipStream_t stream)
{
  (void)in_sizes; (void)n_in; (void)out_size; (void)ws_size;
  const float* x     = (const float*)d_in[0];
  const int*   golds = (const int*)d_in[1];
  const float* wihf  = (const float*)d_in[2];
  const float* whhf  = (const float*)d_in[3];
  const float* bfw   = (const float*)d_in[4];
  const float* wihb  = (const float*)d_in[5];
  const float* whhb  = (const float*)d_in[6];
  const float* bbw   = (const float*)d_in[7];
  const float* swih  = (const float*)d_in[8];
  const float* swhh  = (const float*)d_in[9];
  const float* sb    = (const float*)d_in[10];
  const float* wwih  = (const float*)d_in[11];
  const float* wwhh  = (const float*)d_in[12];
  const float* wb    = (const float*)d_in[13];
  const float* clsW  = (const float*)d_in[14];
  const float* clsb  = (const float*)d_in[15];
  float* out = (float*)d_out;

  char* base = (char*)d_ws;
  // -------- zero-init region (memset each launch) ------------------------------
  u16*   h0   = (u16*)(base + 0);            // 64x1536 bf16 zeros
  u16*   U    = (u16*)(base + 196608);       // triple-buffered 64x2304 bf16
  int*   flg2 = (int*)(base + 1081344);      // bilstm flags: 192 slots * 128 B
  int*   flg4 = (int*)(base + 1105920);      // decode flags
  float* cstf = (float*)(base + 1130496);    // bilstm fwd c-state 64x768 f32
  float* cstb = (float*)(base + 1327104);
  float* scS  = (float*)(base + 1523712);    // decode subword c
  float* wcS  = (float*)(base + 1720320);    // decode word c
  float* whS  = (float*)(base + 1916928);    // decode word h
  // zero region ends at 2,113,536
  // -------- scratch (fully written before read) --------------------------------
  u16* xb     = (u16*)(base + 2113536);
  u16* wihf_b = (u16*)(base + 27279360);
  u16* whhf_b = (u16*)(base + 31997952);
  u16* wihb_b = (u16*)(base + 36716544);
  u16* whhb_b = (u16*)(base + 41435136);
  u16* swih_b = (u16*)(base + 46153728);     // 3072x1536
  u16* swhh_b = (u16*)(base + 55590912);     // 3072x768
  u16* wwrd_b = (u16*)(base + 60309504);     // packed [word_Wih | word_Whh] 3072x2304
  u16* Gfseg  = (u16*)(base + 74465280);     // 4096x3072 bf16 segment
  u16* Gbseg  = (u16*)(base + 99631104);
  u16* lstm   = (u16*)(base + 124796928);    // (B,S,1536) bf16
  // total footprint: 175,128,576 B
  u16* Gsubseg = Gfseg;
  float* prt   = (float*)Gbseg;

  hipMemsetAsync(d_ws, 0, 2113536, stream);

  k_conv<<<16384, 256, 0, stream>>>(x,    xb,     768,  768,  768);
  k_conv<<<3072,  256, 0, stream>>>(wihf, wihf_b, 768,  768,  768);
  k_conv<<<3072,  256, 0, stream>>>(whhf, whhf_b, 768,  768,  768);
  k_conv<<<3072,  256, 0, stream>>>(wihb, wihb_b, 768,  768,  768);
  k_conv<<<3072,  256, 0, stream>>>(whhb, whhb_b, 768,  768,  768);
  k_conv<<<3072,  256, 0, stream>>>(swih, swih_b, 1536, 1536, 1536);
  k_conv<<<3072,  256, 0, stream>>>(swhh, swhh_b, 768,  768,  768);
  k_conv<<<3072,  256, 0, stream>>>(wwih, wwrd_b,        1536, 1536, 2304);
  k_conv<<<3072,  256, 0, stream>>>(wwhh, wwrd_b + 1536, 768,  768,  2304);

  dim3 gg(24, 32);
  for (int sgi = 0; sgi < 4; ++sgi) {
    const int t0f = sgi*SEG;
    const int tb0 = (3 - sgi)*SEG;
    k_gemm<<<gg, 256, 0, stream>>>(xb, wihf_b, bfw, Gfseg, 768, t0f);
    k_gemm<<<gg, 256, 0, stream>>>(xb, wihb_b, bbw, Gbseg, 768, tb0);
    k_bilstm<<<192, 512, 0, stream>>>(Gfseg, Gbseg, whhf_b, whhb_b, h0, lstm,
                                      cstf, cstb, flg2, t0f, tb0, sgi*SEG);
  }

  for (int sgi = 0; sgi < 4; ++sgi) {
    const int r0 = sgi*SEG;
    k_gemm<<<gg, 256, 0, stream>>>(lstm, swih_b, sb, Gsubseg, 1536, r0);
    k_decode<<<192, 512, 0, stream>>>(Gsubseg, swhh_b, wwrd_b, wb, clsW, golds,
                                      U, scS, wcS, whS, prt, flg4, r0);
  }

  dim3 gc(256, 64);
  k_cls<<<gc, 256, 0, stream>>>(lstm, prt, clsW, clsb, out);
}

// Round 6
// 6241.877 us; speedup vs baseline: 1.6781x; 1.6781x over previous
//
#include <hip/hip_runtime.h>

#define B_  64
#define S_  256
#define H_  768
#define H4_ 3072
#define D2_ 1536
#define SEG 64
#define USZ (64*2304)

using u16 = unsigned short;
using u32 = unsigned int;
using u64 = unsigned long long;
typedef __attribute__((ext_vector_type(8))) short bf16x8;
typedef __attribute__((ext_vector_type(4))) float f32x4;
typedef __attribute__((ext_vector_type(4))) unsigned int u32x4;

#define DEV __device__ __forceinline__

DEV float bf2f(u16 u){ union{u32 i; float f;} c; c.i = ((u32)u)<<16; return c.f; }
DEV u16 f2bf(float f){ union{float f; u32 i;} c; c.f = f; return (u16)((c.i + 0x7FFFu + ((c.i>>16)&1u)) >> 16); }
DEV float sigm(float x){ return 1.f/(1.f + __expf(-x)); }
DEV float tanh_(float x){ return 2.f/(1.f + __expf(-2.f*x)) - 1.f; }

// agent-scope publication / flag ops
DEV void astore32(u16* p, u32 v){ __hip_atomic_store((u32*)p, v, __ATOMIC_RELAXED, __HIP_MEMORY_SCOPE_AGENT); }
DEV int afload(const int* p){ return __hip_atomic_load(p, __ATOMIC_RELAXED, __HIP_MEMORY_SCOPE_AGENT); }

DEV f32x4 mfma16(bf16x8 a, bf16x8 b, f32x4 c){
  return __builtin_amdgcn_mfma_f32_16x16x32_bf16(a, b, c, 0, 0, 0);
}

// 96B (48 u16) coherent staging load: 6 x dwordx4 bypassing L1/L2 (sc0 sc1 ->
// LLC-direct), one vmcnt drain. Early-clobber outputs: loads write before the
// last use of the address pair.
DEV void llc_load96(const u16* p, u32x4& a0, u32x4& a1, u32x4& a2,
                    u32x4& a3, u32x4& a4, u32x4& a5){
  asm volatile(
    "global_load_dwordx4 %0, %6, off sc0 sc1\n\t"
    "global_load_dwordx4 %1, %6, off offset:16 sc0 sc1\n\t"
    "global_load_dwordx4 %2, %6, off offset:32 sc0 sc1\n\t"
    "global_load_dwordx4 %3, %6, off offset:48 sc0 sc1\n\t"
    "global_load_dwordx4 %4, %6, off offset:64 sc0 sc1\n\t"
    "global_load_dwordx4 %5, %6, off offset:80 sc0 sc1\n\t"
    "s_waitcnt vmcnt(0)"
    : "=&v"(a0), "=&v"(a1), "=&v"(a2), "=&v"(a3), "=&v"(a4), "=&v"(a5)
    : "v"(p));
}
DEV void stage48llc(u16* dst, const u16* src){
  u32x4 a0,a1,a2,a3,a4,a5;
  llc_load96(src, a0,a1,a2,a3,a4,a5);
  *(u32x4*)(dst)    = a0; *(u32x4*)(dst+8)  = a1;
  *(u32x4*)(dst+16) = a2; *(u32x4*)(dst+24) = a3;
  *(u32x4*)(dst+32) = a4; *(u32x4*)(dst+40) = a5;
}
DEV void stage48llcz(u16* dst, const u16* src, bool keep){
  u32x4 a0,a1,a2,a3,a4,a5;
  llc_load96(src, a0,a1,a2,a3,a4,a5);
  const u32x4 z = {0u,0u,0u,0u};
  if (!keep){ a0=z; a1=z; a2=z; a3=z; a4=z; a5=z; }
  *(u32x4*)(dst)    = a0; *(u32x4*)(dst+8)  = a1;
  *(u32x4*)(dst+16) = a2; *(u32x4*)(dst+24) = a3;
  *(u32x4*)(dst+32) = a4; *(u32x4*)(dst+40) = a5;
}

// 48-wide group barrier; release own flag, poll group's flags with s_sleep.
DEV void gbar48(int* flags, int slot_me, int slot_base, int ep){
  __threadfence_block();          // per-thread vmcnt drain (sc-stores at LLC)
  __syncthreads();
  if (threadIdx.x == 0)
    __hip_atomic_store(&flags[slot_me*64], ep, __ATOMIC_RELEASE, __HIP_MEMORY_SCOPE_AGENT);
  if ((int)threadIdx.x < 48) {
    while (afload(&flags[(slot_base + (int)threadIdx.x)*64]) < ep)
      __builtin_amdgcn_s_sleep(1);
  }
  __syncthreads();
}

// ---------------- fp32 -> bf16 convert (strided dst for packing) ---------------
__global__ void k_conv(const float* __restrict__ src, u16* __restrict__ dst,
                       int cols, int sld, int dld){
  const long r = blockIdx.x;
  for (int c = threadIdx.x*4; c < cols; c += 1024) {
    const float* sp = src + r*sld + c;
    float a = sp[0], b = sp[1], cc = sp[2], d = sp[3];
    u64 pack = (u64)f2bf(a) | ((u64)f2bf(b)<<16) | ((u64)f2bf(cc)<<32) | ((u64)f2bf(d)<<48);
    *(u64*)(dst + r*dld + c) = pack;
  }
}

// ---- C(bf16, 4096x3072) = A[b,t0+tt](bf16) @ W(bf16)^T + bias, 128x128 tile ---
__global__ __launch_bounds__(256) void k_gemm(
    const u16* __restrict__ A, const u16* __restrict__ W,
    const float* __restrict__ bias, u16* __restrict__ C, int K, int t0)
{
  __shared__ u16 at[128*40];
  __shared__ u16 bt[128*40];
  const int tid = threadIdx.x;
  const int L = tid & 63, wv = tid >> 6;
  const int mq = wv >> 1, nq = wv & 1;
  const int l16 = L & 15, quad = L >> 4;
  const long mb = blockIdx.y, nb = blockIdx.x;

  f32x4 acc[4][4];
  #pragma unroll
  for (int m=0;m<4;++m)
    #pragma unroll
    for (int n=0;n<4;++n)
      acc[m][n] = (f32x4){0.f,0.f,0.f,0.f};

  const int r = tid >> 1, c0 = (tid & 1) * 16;
  const int fr = (int)mb*128 + r;
  const long arow = ((long)(fr >> 6))*S_ + t0 + (fr & 63);
  const u16* Arow = A + arow*(long)K + c0;
  const u16* Wrow = W + (nb*128 + r)*(long)K + c0;

  for (int kb = 0; kb < K; kb += 32) {
    *(u32x4*)&at[r*40 + c0]     = *(const u32x4*)(Arow + kb);
    *(u32x4*)&at[r*40 + c0 + 8] = *(const u32x4*)(Arow + kb + 8);
    *(u32x4*)&bt[r*40 + c0]     = *(const u32x4*)(Wrow + kb);
    *(u32x4*)&bt[r*40 + c0 + 8] = *(const u32x4*)(Wrow + kb + 8);
    __syncthreads();
    bf16x8 af[4], bfr[4];
    #pragma unroll
    for (int m=0;m<4;++m) af[m]  = *(const bf16x8*)&at[(mq*64 + m*16 + l16)*40 + quad*8];
    #pragma unroll
    for (int n=0;n<4;++n) bfr[n] = *(const bf16x8*)&bt[(nq*64 + n*16 + l16)*40 + quad*8];
    #pragma unroll
    for (int m=0;m<4;++m)
      #pragma unroll
      for (int n=0;n<4;++n)
        acc[m][n] = mfma16(af[m], bfr[n], acc[m][n]);
    __syncthreads();
  }
  #pragma unroll
  for (int n=0;n<4;++n) {
    const long col = nb*128 + nq*64 + n*16 + l16;
    const float bv = bias[col];
    #pragma unroll
    for (int m=0;m<4;++m) {
      const long row0 = mb*128 + mq*64 + m*16 + quad*4;
      #pragma unroll
      for (int rr=0;rr<4;++rr)
        C[(row0+rr)*3072 + col] = f2bf(acc[m][n][rr] + bv);
    }
  }
}

// ------- persistent bilstm segment: 192 wgs = 2 dirs x 2 bhalf x 48 slices -----
// 512 thr = 8 waves = gate q(4) x k-half kh(2); weights persistent in VGPRs.
// Monolithic full-width staging (proven r3 shape) via LLC-direct 16B loads.
// Barrier groups are 48-wide: (dir,mh) recurrences are independent.
__global__ __launch_bounds__(512,2) void k_bilstm(
    const u16* __restrict__ Gf, const u16* __restrict__ Gb,
    const u16* __restrict__ Whhf, const u16* __restrict__ Whhb,
    const u16* __restrict__ h0, u16* __restrict__ lstm,
    float* __restrict__ cstf, float* __restrict__ cstb,
    int* __restrict__ flags, int t0f, int tb0, int ep0)
{
  __shared__ __align__(16) u16 lds[32*776];   // staged 32x768 (+8 pad)
  float* gbuf = (float*)lds;                  // 16KB alias (post-MFMA)
  const int wg = blockIdx.x;
  const int dir = wg / 96, rem = wg % 96, mh = rem / 48, s = rem % 48;
  const int grp = dir*2 + mh;
  const int tid = threadIdx.x;
  const int wave = tid >> 6, q = wave & 3, kh = wave >> 2;
  const int L = tid & 63, l16 = L & 15, quad = L >> 4;
  const int srw = tid >> 4, scl = (tid & 15) * 48;   // 32 rows x 16 chunks

  const u16* Gsrc = dir ? Gb : Gf;
  const u16* W    = dir ? Whhb : Whhf;
  float* cst      = dir ? cstb : cstf;

  bf16x8 bfr[12];
  {
    const u16* wr = W + (long)(q*H_ + s*16 + l16)*H_ + kh*384 + quad*8;
    #pragma unroll
    for (int kk=0;kk<12;++kk) bfr[kk] = *(const bf16x8*)(wr + kk*32);
  }

  const int lb = tid >> 3, cdl = (tid & 7) * 2;
  const int eb = mh*32 + lb, col = s*16 + cdl;
  const bool ew = (tid < 256);
  float creg[2] = {0.f, 0.f};
  if (ew){ creg[0] = cst[eb*H_ + col]; creg[1] = cst[eb*H_ + col + 1]; }

  u32 g0=0,g1=0,g2=0,g3=0;
  if (ew){
    const int tp0 = dir ? (tb0 + SEG-1) : t0f;
    const int gidx = eb*SEG + (dir ? (tp0 - tb0) : (tp0 - t0f));
    const u16* grow = Gsrc + (long)gidx*H4_ + col;
    g0 = *(const u32*)(grow);      g1 = *(const u32*)(grow + H_);
    g2 = *(const u32*)(grow+2*H_); g3 = *(const u32*)(grow+3*H_);
  }

  for (int t=0; t<SEG; ++t) {
    const int tp = dir ? (tb0 + SEG-1 - t) : (t0f + t);
    const bool first = dir ? (tp == S_-1) : (tp == 0);
    const u16* hbase; long ldh;
    if (first){ hbase = h0 + dir*H_; ldh = D2_; }
    else {
      const int tprev = dir ? (tp+1) : (tp-1);
      hbase = lstm + (long)tprev*D2_ + dir*H_;
      ldh = (long)S_*D2_;
    }
    // monolithic stage 32x768 by all 512 threads
    stage48llc(&lds[srw*776 + scl], hbase + (long)(mh*32 + srw)*ldh + scl);
    __syncthreads();
    f32x4 acc[2];
    acc[0] = (f32x4){0.f,0.f,0.f,0.f}; acc[1] = acc[0];
    #pragma unroll
    for (int kk=0;kk<12;++kk)
      #pragma unroll
      for (int m=0;m<2;++m){
        bf16x8 a = *(const bf16x8*)&lds[(m*16+l16)*776 + kh*384 + kk*32 + quad*8];
        acc[m] = mfma16(a, bfr[kk], acc[m]);
      }
    __syncthreads();
    #pragma unroll
    for (int m=0;m<2;++m)
      #pragma unroll
      for (int rr=0;rr<4;++rr)
        gbuf[(q*2+kh)*512 + (m*16+quad*4+rr)*16 + l16] = acc[m][rr];
    __syncthreads();
    if (ew){
      u32 gr[4] = {g0,g1,g2,g3};
      u32 hp = 0;
      #pragma unroll
      for (int i=0;i<2;++i){
        float gv[4];
        #pragma unroll
        for (int qq=0;qq<4;++qq)
          gv[qq] = gbuf[(qq*2+0)*512 + lb*16 + cdl+i]
                 + gbuf[(qq*2+1)*512 + lb*16 + cdl+i]
                 + bf2f((u16)(gr[qq] >> (16*i)));
        const float c = sigm(gv[1])*creg[i] + sigm(gv[0])*tanh_(gv[2]);
        creg[i] = c;
        const float h = sigm(gv[3])*tanh_(c);
        hp |= ((u32)f2bf(h)) << (16*i);
      }
      astore32(lstm + ((long)eb*S_ + tp)*D2_ + dir*H_ + col, hp);
      // next round's G prefetch overlaps the barrier (last-t value unused)
      const int t2 = t + 1;
      const int tp2 = dir ? (tb0 + SEG-1 - t2) : (t0f + t2);
      const long gidx2 = (long)eb*SEG + (dir ? (tp2 - tb0) : (tp2 - t0f));
      const u16* grow2 = Gsrc + gidx2*H4_ + col;
      g0 = *(const u32*)(grow2);      g1 = *(const u32*)(grow2 + H_);
      g2 = *(const u32*)(grow2+2*H_); g3 = *(const u32*)(grow2+3*H_);
    }
    gbar48(flags, grp*48 + s, grp*48, ep0 + t + 1);
  }
  if (ew){ cst[eb*H_ + col] = creg[0]; cst[eb*H_ + col + 1] = creg[1]; }
}

// -------- persistent decode: 192 wgs = role(sub/word) x 2 bhalf x 48 slices ----
// role0 computes subword(t=r); role1 computes word(t=r-1). 4-deep U ring
// ([h1|c1|Wh] 64x2304): role0 waits {grp(0,mh)>=r, grp(1,mh)>=r-2 (clobber
// guard)}; role1 waits {grp(0,mh)>=r, grp(1,mh)>=r}. Weights in VGPRs.
__global__ __launch_bounds__(512,1) void k_decode(
    const u16* __restrict__ Gsub, const u16* __restrict__ Wsub,
    const u16* __restrict__ Wwrd, const float* __restrict__ wbias,
    const float* __restrict__ clsW, const int* __restrict__ golds,
    u16* __restrict__ U,
    float* __restrict__ scS, float* __restrict__ wcS, float* __restrict__ whS,
    float* __restrict__ partials, int* __restrict__ flags, int r0)
{
  __shared__ __align__(16) u16 ab[2][32*392];
  float* gbuf = (float*)ab;
  const int wg = blockIdx.x;
  const int role = wg / 96, rem = wg % 96, mh = rem / 48, s = rem % 48;
  const int grp = role*2 + mh;
  const int tid = threadIdx.x;
  const int wave = tid >> 6, q = wave & 3, kh = wave >> 2;
  const int L = tid & 63, l16 = L & 15, quad = L >> 4;
  const int su = tid & 255, srw = su >> 3, scl = (su & 7) * 48;
  const int lb = tid >> 3, cdl = (tid & 7)*2;
  const int eb = mh*32 + lb, col = s*16 + cdl;
  const bool ew = (tid < 256);
  const int sb = mh*32 + srw;            // batch of this thread's staged row

  bf16x8 wfr[36];
  float st0[2] = {0.f,0.f}, st1[2] = {0.f,0.f}, st2[2] = {0.f,0.f};
  float wbv[4][2], clv[2][2];
  if (role == 0){
    const u16* wr = Wsub + (long)(q*H_ + s*16 + l16)*H_ + kh*384 + quad*8;
    #pragma unroll
    for (int kk=0;kk<12;++kk) wfr[kk] = *(const bf16x8*)(wr + kk*32);
    if (ew){ st0[0] = scS[eb*H_+col]; st0[1] = scS[eb*H_+col+1]; }
  } else {
    const u16* wr = Wwrd + (long)(q*H_ + s*16 + l16)*2304 + kh*384 + quad*8;
    #pragma unroll
    for (int cc=0;cc<3;++cc)
      #pragma unroll
      for (int kk=0;kk<12;++kk)
        wfr[cc*12+kk] = *(const bf16x8*)(wr + cc*768 + kk*32);
    if (ew){
      st1[0] = wcS[eb*H_+col]; st1[1] = wcS[eb*H_+col+1];
      st2[0] = whS[eb*H_+col]; st2[1] = whS[eb*H_+col+1];
      #pragma unroll
      for (int qq=0;qq<4;++qq){ wbv[qq][0]=wbias[qq*H_+col]; wbv[qq][1]=wbias[qq*H_+col+1]; }
      clv[0][0]=clsW[col]; clv[0][1]=clsW[col+1];
      clv[1][0]=clsW[2304+col]; clv[1][1]=clsW[2304+col+1];
    }
  }

  int stg_g = golds[sb*S_ + ((r0 < 255) ? r0 : 255)];   // staging mask carry (role0)

  for (int rr=0; rr<SEG; ++rr){
    const int r = r0 + rr;
    // ---- decoupled 48-wide waits ----
    if (tid < 96){
      int idx, tgt;
      if (tid < 48){ idx = mh*48 + tid; tgt = r; }
      else { idx = (2+mh)*48 + (tid-48); tgt = (role==0) ? (r-2) : r; }
      while (afload(&flags[idx*64]) < tgt) __builtin_amdgcn_s_sleep(1);
    }
    __syncthreads();

    const u16* Uprev = U + ((r+3)&3)*(long)USZ;
    u16*       Ucur  = U + (r&3)*(long)USZ;

    if (role == 0){
      if (r <= 254){
        u32 g0=0,g1=0,g2=0,g3=0; int gld_e = 0;
        if (ew){
          gld_e = golds[eb*S_ + r + 1];
          const u16* grow = Gsub + ((long)eb*SEG + rr)*H4_ + col;
          g0 = *(const u32*)(grow);      g1 = *(const u32*)(grow + H_);
          g2 = *(const u32*)(grow+2*H_); g3 = *(const u32*)(grow+3*H_);
        }
        const bool keep_s = (r > 0) && (stg_g == 0);
        const u16* urow = Uprev + (long)sb*2304 + scl;
        if (kh == 0){                        // stage masked h1 chunk0
          stage48llcz(&ab[0][srw*392 + scl], urow, keep_s);
        }
        __syncthreads();
        f32x4 acc[2];
        acc[0] = (f32x4){0.f,0.f,0.f,0.f}; acc[1] = acc[0];
        if (kh == 0){
          #pragma unroll
          for (int kk=0;kk<12;++kk)
            #pragma unroll
            for (int m=0;m<2;++m){
              bf16x8 a = *(const bf16x8*)&ab[0][(m*16+l16)*392 + kk*32 + quad*8];
              acc[m] = mfma16(a, wfr[kk], acc[m]);
            }
        } else {                             // stage masked h1 chunk1
          stage48llcz(&ab[1][srw*392 + scl], urow + 384, keep_s);
        }
        __syncthreads();
        if (kh == 1){
          #pragma unroll
          for (int kk=0;kk<12;++kk)
            #pragma unroll
            for (int m=0;m<2;++m){
              bf16x8 a = *(const bf16x8*)&ab[1][(m*16+l16)*392 + kk*32 + quad*8];
              acc[m] = mfma16(a, wfr[kk], acc[m]);
            }
        }
        __syncthreads();
        stg_g = golds[sb*S_ + ((r+1 < 255) ? r+1 : 255)];
        #pragma unroll
        for (int m=0;m<2;++m)
          #pragma unroll
          for (int r4=0;r4<4;++r4)
            gbuf[(q*2+kh)*512 + (m*16+quad*4+r4)*16 + l16] = acc[m][r4];
        __syncthreads();
        if (ew){
          const bool keep = (gld_e == 0);
          u32 gr[4] = {g0,g1,g2,g3};
          u32 hp=0, cp=0;
          #pragma unroll
          for (int i=0;i<2;++i){
            float gv[4];
            #pragma unroll
            for (int qq=0;qq<4;++qq)
              gv[qq] = gbuf[(qq*2+0)*512 + lb*16 + cdl+i]
                     + gbuf[(qq*2+1)*512 + lb*16 + cdl+i]
                     + bf2f((u16)(gr[qq] >> (16*i)));
            const float c1 = sigm(gv[1])*st0[i] + sigm(gv[0])*tanh_(gv[2]);
            const float h1 = sigm(gv[3])*tanh_(c1);
            st0[i] = keep ? c1 : 0.f;
            hp |= ((u32)f2bf(h1)) << (16*i);
            cp |= ((u32)f2bf(c1)) << (16*i);
          }
          astore32(Ucur + (long)eb*2304 + col, hp);
          astore32(Ucur + (long)eb*2304 + H_ + col, cp);
        }
      }
    } else {
      if (r >= 1){
        int gld = 0;
        if (ew) gld = golds[eb*S_ + r];
        const u16* urow = Uprev + (long)sb*2304;
        if (kh == 0){                        // pre-stage chunk0
          stage48llc(&ab[0][srw*392 + scl], urow + scl);
        }
        __syncthreads();
        f32x4 acc[2];
        acc[0] = (f32x4){0.f,0.f,0.f,0.f}; acc[1] = acc[0];
        #pragma unroll
        for (int p=0;p<6;++p){
          if ((p & 1) == kh){                // consume chunk p
            const int cc = p >> 1;
            #pragma unroll
            for (int kk=0;kk<12;++kk)
              #pragma unroll
              for (int m=0;m<2;++m){
                bf16x8 a = *(const bf16x8*)&ab[p&1][(m*16+l16)*392 + kk*32 + quad*8];
                acc[m] = mfma16(a, wfr[cc*12+kk], acc[m]);
              }
          } else if (p < 5){                 // stage chunk p+1
            stage48llc(&ab[(p+1)&1][srw*392 + scl], urow + (p+1)*384 + scl);
          }
          __syncthreads();
        }
        #pragma unroll
        for (int m=0;m<2;++m)
          #pragma unroll
          for (int r4=0;r4<4;++r4)
            gbuf[(q*2+kh)*512 + (m*16+quad*4+r4)*16 + l16] = acc[m][r4];
        __syncthreads();
        if (ew){
          const bool keep = (gld == 0);
          const int tp = r - 1;
          float p0 = 0.f, p1 = 0.f;
          u32 wp = 0;
          #pragma unroll
          for (int i=0;i<2;++i){
            float gv[4];
            #pragma unroll
            for (int qq=0;qq<4;++qq)
              gv[qq] = gbuf[(qq*2+0)*512 + lb*16 + cdl+i]
                     + gbuf[(qq*2+1)*512 + lb*16 + cdl+i]
                     + wbv[qq][i];
            const float wc1 = sigm(gv[1])*st1[i] + sigm(gv[0])*tanh_(gv[2]);
            const float wh1 = sigm(gv[3])*tanh_(wc1);
            st1[i] = keep ? st1[i] : wc1;
            st2[i] = keep ? st2[i] : wh1;
            p0 += wh1 * clv[0][i];
            p1 += wh1 * clv[1][i];
            wp |= ((u32)f2bf(st2[i])) << (16*i);
          }
          astore32(Ucur + (long)eb*2304 + D2_ + col, wp);
          p0 += __shfl_xor(p0, 1); p0 += __shfl_xor(p0, 2); p0 += __shfl_xor(p0, 4);
          p1 += __shfl_xor(p1, 1); p1 += __shfl_xor(p1, 2); p1 += __shfl_xor(p1, 4);
          if ((tid & 7) == 0){
            float* pp = partials + ((long)(tp*48 + s)*64 + eb)*2;
            pp[0] = p0; pp[1] = p1;
          }
        }
      }
    }
    // ---- release own flag ----
    __threadfence_block();
    __syncthreads();
    if (tid == 0)
      __hip_atomic_store(&flags[(grp*48 + s)*64], r+1, __ATOMIC_RELEASE, __HIP_MEMORY_SCOPE_AGENT);
  }
  if (ew){
    if (role == 0){
      scS[eb*H_+col] = st0[0]; scS[eb*H_+col+1] = st0[1];
    } else {
      wcS[eb*H_+col] = st1[0]; wcS[eb*H_+col+1] = st1[1];
      whS[eb*H_+col] = st2[0]; whS[eb*H_+col+1] = st2[1];
    }
  }
}

// ---------------- classifier epilogue: out = first | cls_b + wh-part + x-part --
__global__ __launch_bounds__(256) void k_cls(
    const u16* __restrict__ lstm, const float* __restrict__ partials,
    const float* __restrict__ clsW, const float* __restrict__ clsb,
    float* __restrict__ out)
{
  const int ts = blockIdx.x;
  const int b  = blockIdx.y;
  const int tid = threadIdx.x;
  if (ts == 0) {
    if (tid == 0) { out[(long)b*S_*2 + 0] = -1.f; out[(long)b*S_*2 + 1] = 1.f; }
    return;
  }
  const int t = ts - 1;
  float s0 = 0.f, s1 = 0.f;
  const u16* xr = lstm + ((long)b*S_ + ts)*D2_;
  for (int k = tid; k < D2_; k += 256) {
    const float xv = bf2f(xr[k]);
    s0 += xv * clsW[768 + k];
    s1 += xv * clsW[2304 + 768 + k];
  }
  if (tid < 48) {
    const float* pr = partials + ((long)(t*48 + tid)*64 + b)*2;
    s0 += pr[0]; s1 += pr[1];
  }
  __shared__ float r0[256], r1[256];
  r0[tid] = s0; r1[tid] = s1; __syncthreads();
  for (int off = 128; off > 0; off >>= 1) {
    if (tid < off) { r0[tid] += r0[tid+off]; r1[tid] += r1[tid+off]; }
    __syncthreads();
  }
  if (tid == 0) {
    out[((long)b*S_ + ts)*2 + 0] = r0[0] + clsb[0];
    out[((long)b*S_ + ts)*2 + 1] = r1[0] + clsb[1];
  }
}

extern "C" void kernel_launch(void* const* d_in, const int* in_sizes, int n_in,
                              void* d_out, int out_size, void* d_ws, size_t ws_size,
                              hipStream_t stream)
{
  (void)in_sizes; (void)n_in; (void)out_size; (void)ws_size;
  const float* x     = (const float*)d_in[0];
  const int*   golds = (const int*)d_in[1];
  const float* wihf  = (const float*)d_in[2];
  const float* whhf  = (const float*)d_in[3];
  const float* bfw   = (const float*)d_in[4];
  const float* wihb  = (const float*)d_in[5];
  const float* whhb  = (const float*)d_in[6];
  const float* bbw   = (const float*)d_in[7];
  const float* swih  = (const float*)d_in[8];
  const float* swhh  = (const float*)d_in[9];
  const float* sb    = (const float*)d_in[10];
  const float* wwih  = (const float*)d_in[11];
  const float* wwhh  = (const float*)d_in[12];
  const float* wb    = (const float*)d_in[13];
  const float* clsW  = (const float*)d_in[14];
  const float* clsb  = (const float*)d_in[15];
  float* out = (float*)d_out;

  char* base = (char*)d_ws;
  // -------- zero-init region (memset each launch) ------------------------------
  u16*   U    = (u16*)(base + 0);            // 4-deep ring of 64x2304 bf16
  u16*   h0   = (u16*)(base + 0);            // aliases U[0]: zeros during bilstm
  int*   flg2 = (int*)(base + 1179648);      // bilstm flags: 192 slots * 256 B
  int*   flg4 = (int*)(base + 1228800);      // decode flags
  float* cstf = (float*)(base + 1277952);    // bilstm fwd c-state 64x768 f32
  float* cstb = (float*)(base + 1474560);
  float* scS  = (float*)(base + 1671168);    // decode subword c
  float* wcS  = (float*)(base + 1867776);    // decode word c
  float* whS  = (float*)(base + 2064384);    // decode word h
  // zero region ends at 2,260,992
  // -------- scratch (fully written before read) --------------------------------
  u16* xb     = (u16*)(base + 2260992);
  u16* wihf_b = (u16*)(base + 27426816);
  u16* whhf_b = (u16*)(base + 32145408);
  u16* wihb_b = (u16*)(base + 36864000);
  u16* whhb_b = (u16*)(base + 41582592);
  u16* swih_b = (u16*)(base + 46301184);     // 3072x1536
  u16* swhh_b = (u16*)(base + 55738368);     // 3072x768
  u16* wwrd_b = (u16*)(base + 60456960);     // packed [word_Wih | word_Whh] 3072x2304
  u16* Gfseg  = (u16*)(base + 74612736);     // 4096x3072 bf16 segment
  u16* Gbseg  = (u16*)(base + 99778560);
  u16* lstm   = (u16*)(base + 124944384);    // (B,S,1536) bf16
  // total footprint: 175,276,032 B
  u16* Gsubseg = Gfseg;
  float* prt   = (float*)Gbseg;

  hipMemsetAsync(d_ws, 0, 2260992, stream);

  k_conv<<<16384, 256, 0, stream>>>(x,    xb,     768,  768,  768);
  k_conv<<<3072,  256, 0, stream>>>(wihf, wihf_b, 768,  768,  768);
  k_conv<<<3072,  256, 0, stream>>>(whhf, whhf_b, 768,  768,  768);
  k_conv<<<3072,  256, 0, stream>>>(wihb, wihb_b, 768,  768,  768);
  k_conv<<<3072,  256, 0, stream>>>(whhb, whhb_b, 768,  768,  768);
  k_conv<<<3072,  256, 0, stream>>>(swih, swih_b, 1536, 1536, 1536);
  k_conv<<<3072,  256, 0, stream>>>(swhh, swhh_b, 768,  768,  768);
  k_conv<<<3072,  256, 0, stream>>>(wwih, wwrd_b,        1536, 1536, 2304);
  k_conv<<<3072,  256, 0, stream>>>(wwhh, wwrd_b + 1536, 768,  768,  2304);

  dim3 gg(24, 32);
  for (int sgi = 0; sgi < 4; ++sgi) {
    const int t0f = sgi*SEG;
    const int tb0 = (3 - sgi)*SEG;
    k_gemm<<<gg, 256, 0, stream>>>(xb, wihf_b, bfw, Gfseg, 768, t0f);
    k_gemm<<<gg, 256, 0, stream>>>(xb, wihb_b, bbw, Gbseg, 768, tb0);
    k_bilstm<<<192, 512, 0, stream>>>(Gfseg, Gbseg, whhf_b, whhb_b, h0, lstm,
                                      cstf, cstb, flg2, t0f, tb0, sgi*SEG);
  }

  for (int sgi = 0; sgi < 4; ++sgi) {
    const int r0 = sgi*SEG;
    k_gemm<<<gg, 256, 0, stream>>>(lstm, swih_b, sb, Gsubseg, 1536, r0);
    k_decode<<<192, 512, 0, stream>>>(Gsubseg, swhh_b, wwrd_b, wb, clsW, golds,
                                      U, scS, wcS, whS, prt, flg4, r0);
  }

  dim3 gc(256, 64);
  k_cls<<<gc, 256, 0, stream>>>(lstm, prt, clsW, clsb, out);
}